// Round 13
// baseline (315.002 us; speedup 1.0000x reference)
//
#include <hip/hip_runtime.h>
#include <math.h>

// Problem constants (B=1 fixed by reference)
#define NP 9216          // S*S spatial positions
#define DC 256           // channels
#define DN (DC * NP)
#define NTB 36           // 9216 / 256 tiles per dim
#define KCH (NP * 32)    // halves per k-chunk section of a plane

#define FEPS 2.220446049250313e-16f

typedef __attribute__((ext_vector_type(8)))  _Float16 half8v;
typedef __attribute__((ext_vector_type(4)))  float    float4v;
typedef __attribute__((ext_vector_type(16))) float    float16v;

union HU { _Float16 h; unsigned short u; };
__device__ __forceinline__ unsigned short f2h(float f) { HU x; x.h = (_Float16)f; return x.u; }
__device__ __forceinline__ float h2f(unsigned short s) { HU x; x.u = s; return (float)x.h; }

// Plane layout (k-major): half index off(n,k) = (k>>5)*KCH + n*32 + (k&31)
// Split (same scale): s' = v*inv*2^8; H = fp16(s'), R = fp16(s' - H).
// sim*2^16 = Hx.Hy + Hx.Ry + Rx.Hy (Rx.Ry dropped, ~2^-22 rel).
//
// R13: shape swap 16x16x32 -> 32x32x16 in ksim. Fixed FLOPs, but half the
// MFMA instructions (24 vs 48 per wave per kt) at ~2x FLOP/instr; measured
// rates (m119 2495 vs 2075 TF) => -17% matrix-pipe issue cycles. LDS reads
// unchanged (16 x b128 per wave per kt, fragments still 16B/lane; bank
// balance re-verified under the same (row>>1)&3 swizzle). Register budget
// kept at the 128/wave cap (16 resident waves) via ks-pairwise A reads and
// a per-tm split epilogue. C/D map (verified m74/m101): col=lane&31,
// row=(reg&3)+8*(reg>>2)+4*(lane>>5). Same product set, same ascending-k
// accumulation order (grouped by 16 instead of 32 -> ~1ulp f32 shift).

// ---------------- Kernel 1: fused normalize + fp16 H/R split ----------------
__global__ __launch_bounds__(256) void kprep(
    const float* __restrict__ X, const float* __restrict__ Y,
    float* __restrict__ Xf_out,
    unsigned short* __restrict__ XH, unsigned short* __restrict__ XR,
    unsigned short* __restrict__ YH, unsigned short* __restrict__ YR,
    unsigned long long* __restrict__ nnkey, float* __restrict__ lacc)
{
    __shared__ float tile[64 * 257];   // (n, d) at n*257+d
    __shared__ float psum[4][64];
    __shared__ float invs[64];

    const int t = threadIdx.x;
    const bool isX = (blockIdx.y == 0);
    const float* src = isX ? X : Y;
    unsigned* hT = (unsigned*)(isX ? XH : YH);
    unsigned* rT = (unsigned*)(isX ? XR : YR);
    const int n0 = blockIdx.x * 64;

    if (blockIdx.x == 0 && blockIdx.y == 0 && t == 0) *lacc = 0.0f;
    if (isX && t < 64) nnkey[n0 + t] = 0ull;   // min key: any real value wins

    const int lane = t & 63;
    const int w    = t >> 6;      // wave id -> owns d-range [w*64, w*64+64)

    #pragma unroll 8
    for (int i = 0; i < 64; ++i) {
        int d = w * 64 + i;
        tile[lane * 257 + d] = src[(size_t)d * NP + n0 + lane];
    }
    float s = 0.0f;
    #pragma unroll 8
    for (int i = 0; i < 64; ++i) {
        float v = tile[lane * 257 + w * 64 + i];
        s = fmaf(v, v, s);
    }
    psum[w][lane] = s;
    __syncthreads();
    if (t < 64) {
        float tot = psum[0][t] + psum[1][t] + psum[2][t] + psum[3][t];
        invs[t] = 1.0f / (sqrtf(tot) + FEPS);
    }
    __syncthreads();

    // plane writes, k-major layout; coalesced uints.
    for (int kt = 0; kt < 8; ++kt) {
        #pragma unroll
        for (int p = 0; p < 4; ++p) {
            int idx = p * 256 + t;
            int n = idx >> 4;          // 0..63
            int u = idx & 15;          // uint within chunk (2 halves)
            float inv = invs[n] * 256.0f;
            int d = kt * 32 + 2 * u;
            float s0 = tile[n * 257 + d] * inv;
            float s1 = tile[n * 257 + d + 1] * inv;
            unsigned short h0 = f2h(s0), h1 = f2h(s1);
            unsigned short r0 = f2h(s0 - h2f(h0));
            unsigned short r1 = f2h(s1 - h2f(h1));
            size_t uo = (size_t)kt * (NP * 16) + (size_t)(n0 + n) * 16 + u;
            hT[uo] = (unsigned)h0 | ((unsigned)h1 << 16);
            rT[uo] = (unsigned)r0 | ((unsigned)r1 << 16);
        }
    }

    // exact fp32 Xf output ([d][n], coalesced over n)
    if (isX) {
        const float inv = invs[lane];
        #pragma unroll 8
        for (int i = 0; i < 64; ++i) {
            int d = w * 64 + i;
            Xf_out[(size_t)d * NP + n0 + lane] = tile[lane * 257 + d] * inv;
        }
    }
}

// ---------------- Kernel 2: 256x256 LDS GEMM (32x32x16) + atomic argmax ----
__device__ __forceinline__ void glds16(const char* g, char* l)
{
    __builtin_amdgcn_global_load_lds(
        (const __attribute__((address_space(1))) void*)g,
        (__attribute__((address_space(3))) void*)l, 16, 0, 0);
}

__global__ __launch_bounds__(1024, 4) void ksim(
    const unsigned short* __restrict__ XH,
    const unsigned short* __restrict__ YH,
    unsigned long long* __restrict__ nnkey)
{
    extern __shared__ char smem[];   // 2 x (A 32K | B 32K) = 128 KB

    const int t = threadIdx.x;
    const size_t PLB = 2 * (size_t)DN;            // H -> R plane byte offset
    const size_t KTB = 2 * (size_t)KCH;           // per-kt chunk byte stride

    // ---- XCD swizzle: 1296 blocks = 8 XCD x 162 (9 cols x 18 rows patch) --
    const int lid = blockIdx.y * NTB + blockIdx.x;
    const int xcd = lid & 7;
    const int r   = lid >> 3;                  // 0..161
    const int ti  = (xcd >> 2) * 18 + r / 9;   // row tile 0..35
    const int tj  = (xcd & 3) * 9 + r % 9;     // col tile 0..35
    const int n0  = ti * 256;                  // X rows
    const int m0  = tj * 256;                  // Y cols

    const int L = t & 63, wid = t >> 6;        // 16 waves: 4M x 4N
    const int wm = wid >> 2, wn = wid & 3;     // wave tile 64x64 = 2x2 of 32x32
    const int lr = L & 31, l5 = L >> 5;

    // staging: per-thread 16B seg; source inverse-swizzled (R6-verified
    // involution: XOR bits 4-5 of in-row offset with (row>>1)&3)
    const char* Ab = (const char*)XH + (size_t)n0 * 64;
    const char* Bb = (const char*)YH + (size_t)m0 * 64;
    const int dOf = t * 16;
    const int dSw = dOf ^ (((dOf >> 7) & 3) << 4);

    float16v acc[2][2];
    #pragma unroll
    for (int i = 0; i < 2; ++i)
        #pragma unroll
        for (int j = 0; j < 2; ++j)
            #pragma unroll
            for (int e = 0; e < 16; ++e)
                acc[i][j][e] = 0.0f;

    // ---- prologue: stage kt0 ----
    glds16(Ab + dSw,       smem + dOf);
    glds16(Ab + PLB + dSw, smem + 16384 + dOf);
    glds16(Bb + dSw,       smem + 32768 + dOf);
    glds16(Bb + PLB + dSw, smem + 49152 + dOf);
    __syncthreads();

    // fragment addressing: 32x32x16 A/B layout = lane holds row (lane&31),
    // k-bytes = ks*32 + (lane>>5)*16 within the row's 64B kt-chunk.
    // Same swizzle involution as staging: XOR bits 4-5 with (row>>1)&3.
    const int swz   = ((lr >> 1) & 3) << 4;
    const int koff0 = (l5 * 16) ^ swz;            // ks = 0
    const int koff1 = (32 + l5 * 16) ^ swz;       // ks = 1
    const int arowb = (wm * 64 + lr) * 64;        // + tm*2048 selects row block
    const int browb = (wn * 64 + lr) * 64;        // + tn*2048

    #pragma unroll 1
    for (int kt = 0; kt < 8; ++kt) {
        const char* cur = smem + (kt & 1) * 65536;

        if (kt < 7) {   // stage kt+1 into the other buffer (in flight across MFMAs)
            char* nxt = smem + ((kt + 1) & 1) * 65536;
            const size_t kb = (size_t)(kt + 1) * KTB;
            glds16(Ab + kb + dSw,       nxt + dOf);
            glds16(Ab + PLB + kb + dSw, nxt + 16384 + dOf);
            glds16(Bb + kb + dSw,       nxt + 32768 + dOf);
            glds16(Bb + PLB + kb + dSw, nxt + 49152 + dOf);
        }

        // ---- B register block: all 8 B frags live (32 VGPR), read ONCE ----
        half8v Bh[2][2], Br[2][2];                 // [tn][ks]
        #pragma unroll
        for (int tn = 0; tn < 2; ++tn) {
            Bh[tn][0] = *(const half8v*)(cur + 32768 + browb + tn * 2048 + koff0);
            Bh[tn][1] = *(const half8v*)(cur + 32768 + browb + tn * 2048 + koff1);
            Br[tn][0] = *(const half8v*)(cur + 49152 + browb + tn * 2048 + koff0);
            Br[tn][1] = *(const half8v*)(cur + 49152 + browb + tn * 2048 + koff1);
        }

        // ---- tm-outer, ks-pairwise A reads (8 A-reads/kt, transient 8 VGPR)
        __builtin_amdgcn_s_setprio(1);
        #pragma unroll
        for (int tm = 0; tm < 2; ++tm) {
            {   // ks = 0
                half8v Ah = *(const half8v*)(cur +         arowb + tm * 2048 + koff0);
                half8v Ar = *(const half8v*)(cur + 16384 + arowb + tm * 2048 + koff0);
                #pragma unroll
                for (int tn = 0; tn < 2; ++tn) {
                    float16v v = acc[tm][tn];
                    v = __builtin_amdgcn_mfma_f32_32x32x16_f16(Ah, Bh[tn][0], v, 0, 0, 0);
                    v = __builtin_amdgcn_mfma_f32_32x32x16_f16(Ah, Br[tn][0], v, 0, 0, 0);
                    v = __builtin_amdgcn_mfma_f32_32x32x16_f16(Ar, Bh[tn][0], v, 0, 0, 0);
                    acc[tm][tn] = v;
                }
            }
            {   // ks = 1
                half8v Ah = *(const half8v*)(cur +         arowb + tm * 2048 + koff1);
                half8v Ar = *(const half8v*)(cur + 16384 + arowb + tm * 2048 + koff1);
                #pragma unroll
                for (int tn = 0; tn < 2; ++tn) {
                    float16v v = acc[tm][tn];
                    v = __builtin_amdgcn_mfma_f32_32x32x16_f16(Ah, Bh[tn][1], v, 0, 0, 0);
                    v = __builtin_amdgcn_mfma_f32_32x32x16_f16(Ah, Br[tn][1], v, 0, 0, 0);
                    v = __builtin_amdgcn_mfma_f32_32x32x16_f16(Ar, Bh[tn][1], v, 0, 0, 0);
                    acc[tm][tn] = v;
                }
            }
        }
        __builtin_amdgcn_s_setprio(0);

        if (kt < 7) __syncthreads();   // drains next-tile DMA (had full MFMA phase)
    }

    // ---- epilogue: per-row argmax over this wave's 64 cols ----
    // 32x32 C/D map (m74/m101): col = lane&31, row = (reg&3)+8*(reg>>2)+4*(lane>>5).
    // Per-tm split keeps register pressure under the 128/wave cap.
    float* v2s = (float*)smem;          // reuses buf0 (last read kt6; barrier passed)
    int*   i2s = (int*)(smem + 4096);

    #pragma unroll
    for (int tm = 0; tm < 2; ++tm) {
        float bv[16]; int bc[16];
        #pragma unroll
        for (int s = 0; s < 16; ++s) { bv[s] = -INFINITY; bc[s] = 0; }

        #pragma unroll
        for (int tn = 0; tn < 2; ++tn) {    // tn ascending = col ascending
            const int col = m0 + wn * 64 + tn * 32 + lr;
            #pragma unroll
            for (int reg = 0; reg < 16; ++reg) {
                float v = acc[tm][tn][reg];
                if (v > bv[reg]) { bv[reg] = v; bc[reg] = col; }
            }
        }

        // reduce across the 32 col-lanes (xor<32 stays within each half-wave;
        // the two halves hold different rows)
        #pragma unroll
        for (int off = 1; off < 32; off <<= 1) {
            #pragma unroll
            for (int s = 0; s < 16; ++s) {
                float ov = __shfl_xor(bv[s], off, 64);
                int   oi = __shfl_xor(bc[s], off, 64);
                if (ov > bv[s] || (ov == bv[s] && oi < bc[s])) { bv[s] = ov; bc[s] = oi; }
            }
        }

        if (lr == 0) {   // lanes 0 and 32 write disjoint rows
            #pragma unroll
            for (int reg = 0; reg < 16; ++reg) {
                int row = wm * 64 + tm * 32 + (reg & 3) + 8 * (reg >> 2) + 4 * l5;
                v2s[row * 4 + wn] = bv[reg];
                i2s[row * 4 + wn] = bc[reg];
            }
        }
    }
    __syncthreads();
    if (t < 256) {
        // wn ascending = col ascending: strict '>' keeps first-max semantics.
        float b = v2s[t * 4]; int bi = i2s[t * 4];
        #pragma unroll
        for (int q = 1; q < 4; ++q) {
            float v = v2s[t * 4 + q];
            if (v > b) { b = v; bi = i2s[t * 4 + q]; }
        }
        // packed atomic argmax: key = monotone(b)<<32 | ~col.
        // max key == max value; on equal value, max(~col) == min col ==
        // first-max semantics (identical to the old kred).
        unsigned uv = __float_as_uint(b);
        uv = (uv & 0x80000000u) ? ~uv : (uv | 0x80000000u);
        unsigned long long key =
            ((unsigned long long)uv << 32) | (unsigned)(0xFFFFFFFFu - (unsigned)bi);
        atomicMax(nnkey + n0 + t, key);
    }
}

// ---------------- Kernel 3: gather Y_sel + fused MSE loss ----------------
// y = (H + R) * 2^-8 (H/R same scale; error ~2^-22 relative).
__global__ __launch_bounds__(256) void kgather(
    const unsigned short* __restrict__ YH, const unsigned short* __restrict__ YR,
    const unsigned long long* __restrict__ nnkey,
    const float* __restrict__ Xf, float* __restrict__ Ysel,
    float* __restrict__ lacc)
{
    __shared__ float tile[64][65];
    __shared__ int   idxs[64];
    __shared__ float wsum[4];

    const int n0 = blockIdx.x * 64;
    const int d0 = blockIdx.y * 64;
    const int tid = threadIdx.x;

    if (tid < 64) {
        unsigned long long k = nnkey[n0 + tid];
        idxs[tid] = (int)(0xFFFFFFFFu - (unsigned)(k & 0xFFFFFFFFull));
    }
    __syncthreads();

    const int c  = tid & 63;
    const int r0 = tid >> 6;

    #pragma unroll
    for (int s = 0; s < 16; ++s) {
        int r = s * 4 + r0;
        int d = d0 + c;
        size_t off = (size_t)(d >> 5) * KCH + (size_t)idxs[r] * 32 + (d & 31);
        tile[r][c] = (h2f(YH[off]) + h2f(YR[off])) * (1.0f / 256.0f);
    }
    __syncthreads();

    float lsum = 0.0f;
    #pragma unroll
    for (int s = 0; s < 16; ++s) {
        int a = s * 4 + r0;
        int d = d0 + a;
        int n = n0 + c;
        float y = tile[c][a];          // stride-65: conflict-free
        float x = Xf[(size_t)d * NP + n];
        float diff = x - y;
        lsum = fmaf(diff, diff, lsum);
        Ysel[(size_t)d * NP + n] = y;  // coalesced over n
    }

    #pragma unroll
    for (int off = 32; off >= 1; off >>= 1)
        lsum += __shfl_xor(lsum, off, 64);
    if ((tid & 63) == 0) wsum[tid >> 6] = lsum;
    __syncthreads();
    if (tid == 0)
        atomicAdd(lacc, wsum[0] + wsum[1] + wsum[2] + wsum[3]);
}

// ---------------- Kernel 4: finalize loss ----------------
__global__ void kfin(const float* __restrict__ lacc, float* __restrict__ out)
{
    out[0] = lacc[0] * (1.0f / (float)DN);
}

extern "C" void kernel_launch(void* const* d_in, const int* in_sizes, int n_in,
                              void* d_out, int out_size, void* d_ws, size_t ws_size,
                              hipStream_t stream)
{
    const float* X = (const float*)d_in[0];   // X_features [1,256,96,96]
    const float* Y = (const float*)d_in[1];   // Y_features [1,256,96,96]
    // d_in[2], d_in[3] (images) are dead code in the reference — unused.

    float* out = (float*)d_out;
    float* Ysel_out = out + 1;          // output 1: Y_sel [1,D,N]
    float* Xf_out   = out + 1 + DN;     // output 2: Xf   [1,D,N]  (exact fp32)

    // Workspace (~19 MB). XH|XR and YH|YR MUST be contiguous pairs
    // (ksim derives R = H + 2*DN bytes). nnkey offset is 8*DN bytes (8B-aligned).
    unsigned short* XH = (unsigned short*)d_ws;   // DN halves each
    unsigned short* XR = XH + DN;
    unsigned short* YH = XR + DN;
    unsigned short* YR = YH + DN;
    unsigned long long* nnkey = (unsigned long long*)(YR + DN);   // NP u64
    float* lacc = (float*)(nnkey + NP);                           // 1

    static bool attr_done = false;
    if (!attr_done) {
        hipFuncSetAttribute(reinterpret_cast<const void*>(ksim),
                            hipFuncAttributeMaxDynamicSharedMemorySize, 131072);
        attr_done = true;
    }

    hipLaunchKernelGGL(kprep, dim3(NP / 64, 2), dim3(256), 0, stream,
                       X, Y, Xf_out, XH, XR, YH, YR, nnkey, lacc);
    hipLaunchKernelGGL(ksim, dim3(NTB, NTB), dim3(1024), 131072, stream,
                       XH, YH, nnkey);
    hipLaunchKernelGGL(kgather, dim3(NP / 64, DC / 64), dim3(256), 0, stream,
                       YH, YR, nnkey, Xf_out, Ysel_out, lacc);
    hipLaunchKernelGGL(kfin, dim3(1), dim3(1), 0, stream, lacc, out);
}

// Round 14
// 286.503 us; speedup vs baseline: 1.0995x; 1.0995x over previous
//
#include <hip/hip_runtime.h>
#include <math.h>

// Problem constants (B=1 fixed by reference)
#define NP 9216          // S*S spatial positions
#define DC 256           // channels
#define DN (DC * NP)
#define TS 144           // ksim tile size
#define NTB 64           // 9216 / 144 tiles per dim
#define KCH (NP * 32)    // halves per k-chunk section of a plane

#define FEPS 2.220446049250313e-16f

typedef __attribute__((ext_vector_type(8))) _Float16 half8v;
typedef __attribute__((ext_vector_type(4))) float   float4v;

union HU { _Float16 h; unsigned short u; };
__device__ __forceinline__ unsigned short f2h(float f) { HU x; x.h = (_Float16)f; return x.u; }
__device__ __forceinline__ float h2f(unsigned short s) { HU x; x.u = s; return (float)x.h; }

// Plane layout (k-major): half index off(n,k) = (k>>5)*KCH + n*32 + (k&31)
// Split (same scale): s' = v*inv*2^8; H = fp16(s'), R = fp16(s' - H).
// sim*2^16 = Hx.Hy + Hx.Ry + Rx.Hy (Rx.Ry dropped, ~2^-22 rel).
//
// R14: R13's 32x32 shape reverted (bank conflicts 74x: 32-row x 2-slot
// reads defeat the 2-bit swizzle -- structural, unfixable in this layout).
// R12 makespan analysis: 1296 blocks at 1 block/CU = 6 rounds for 5.06
// rounds of work -> ~25us pure tail; and the 37% MfmaUtil plateau is the
// single resident block's barrier convoy. Fix both with 144x144 tiles:
//   grid 64x64 = 4096 = 16x256 (exact); LDS 72KB dbuf -> 2 blocks/CU
//   (8.0 exact rounds; 1-block fallback = 16.0 exact rounds -- tail-free
//   either way); 2 independent blocks/CU overlap each other's barrier
//   stalls (m114 co-scheduling). 9 waves of 48x48; 27 MFMA + 12 ds_read
//   per wave per kt; staging exactly 4 glds16/thread. Same fragment
//   pattern/swizzle/chain order as R12 -> bit-identical numerics.

// ---------------- Kernel 1: fused normalize + fp16 H/R split ----------------
__global__ __launch_bounds__(256) void kprep(
    const float* __restrict__ X, const float* __restrict__ Y,
    float* __restrict__ Xf_out,
    unsigned short* __restrict__ XH, unsigned short* __restrict__ XR,
    unsigned short* __restrict__ YH, unsigned short* __restrict__ YR,
    unsigned long long* __restrict__ nnkey, float* __restrict__ lacc)
{
    __shared__ float tile[64 * 257];   // (n, d) at n*257+d
    __shared__ float psum[4][64];
    __shared__ float invs[64];

    const int t = threadIdx.x;
    const bool isX = (blockIdx.y == 0);
    const float* src = isX ? X : Y;
    unsigned* hT = (unsigned*)(isX ? XH : YH);
    unsigned* rT = (unsigned*)(isX ? XR : YR);
    const int n0 = blockIdx.x * 64;

    if (blockIdx.x == 0 && blockIdx.y == 0 && t == 0) *lacc = 0.0f;
    if (isX && t < 64) nnkey[n0 + t] = 0ull;   // min key: any real value wins

    const int lane = t & 63;
    const int w    = t >> 6;      // wave id -> owns d-range [w*64, w*64+64)

    #pragma unroll 8
    for (int i = 0; i < 64; ++i) {
        int d = w * 64 + i;
        tile[lane * 257 + d] = src[(size_t)d * NP + n0 + lane];
    }
    float s = 0.0f;
    #pragma unroll 8
    for (int i = 0; i < 64; ++i) {
        float v = tile[lane * 257 + w * 64 + i];
        s = fmaf(v, v, s);
    }
    psum[w][lane] = s;
    __syncthreads();
    if (t < 64) {
        float tot = psum[0][t] + psum[1][t] + psum[2][t] + psum[3][t];
        invs[t] = 1.0f / (sqrtf(tot) + FEPS);
    }
    __syncthreads();

    // plane writes, k-major layout; coalesced uints.
    for (int kt = 0; kt < 8; ++kt) {
        #pragma unroll
        for (int p = 0; p < 4; ++p) {
            int idx = p * 256 + t;
            int n = idx >> 4;          // 0..63
            int u = idx & 15;          // uint within chunk (2 halves)
            float inv = invs[n] * 256.0f;
            int d = kt * 32 + 2 * u;
            float s0 = tile[n * 257 + d] * inv;
            float s1 = tile[n * 257 + d + 1] * inv;
            unsigned short h0 = f2h(s0), h1 = f2h(s1);
            unsigned short r0 = f2h(s0 - h2f(h0));
            unsigned short r1 = f2h(s1 - h2f(h1));
            size_t uo = (size_t)kt * (NP * 16) + (size_t)(n0 + n) * 16 + u;
            hT[uo] = (unsigned)h0 | ((unsigned)h1 << 16);
            rT[uo] = (unsigned)r0 | ((unsigned)r1 << 16);
        }
    }

    // exact fp32 Xf output ([d][n], coalesced over n)
    if (isX) {
        const float inv = invs[lane];
        #pragma unroll 8
        for (int i = 0; i < 64; ++i) {
            int d = w * 64 + i;
            Xf_out[(size_t)d * NP + n0 + lane] = tile[lane * 257 + d] * inv;
        }
    }
}

// ---------------- Kernel 2: 144x144 both-in-LDS MFMA GEMM + atomic argmax --
// Per-kt buffer: A-H | A-R | B-H | B-R, 9216 B each (36864 B); double = 72 KB.
__device__ __forceinline__ void glds16(const char* g, char* l)
{
    __builtin_amdgcn_global_load_lds(
        (const __attribute__((address_space(1))) void*)g,
        (__attribute__((address_space(3))) void*)l, 16, 0, 0);
}

__global__ __launch_bounds__(576, 4) void ksim(
    const unsigned short* __restrict__ XH,
    const unsigned short* __restrict__ YH,
    unsigned long long* __restrict__ nnkey)
{
    extern __shared__ char smem[];   // 2 x 36864 B

    const int t = threadIdx.x;
    const size_t PLB = 2 * (size_t)DN;            // H -> R plane byte offset
    const size_t KTB = 2 * (size_t)KCH;           // per-kt chunk byte stride

    // ---- XCD swizzle: 4096 blocks = 8 XCD x 512 (32 ti x 16 tj patch) ----
    const int lid = blockIdx.y * NTB + blockIdx.x;
    const int xcd = lid & 7;
    const int r   = lid >> 3;                   // 0..511
    const int ti  = (xcd >> 2) * 32 + (r >> 4); // row tile 0..63
    const int tj  = (xcd & 3) * 16 + (r & 15);  // col tile 0..63
    const int n0  = ti * TS;                    // X rows
    const int m0  = tj * TS;                    // Y cols

    const int L = t & 63, wid = t >> 6;         // 9 waves: 3M x 3N
    const int wm = wid / 3, wn = wid - wm * 3;  // wave tile 48x48
    const int lc = L & 15,  lq = L >> 4;

    // staging: 4 x 16B segs/thread (one per part); source inverse-swizzled
    // (R6-verified involution: XOR bits 4-5 of in-row offset with (row>>1)&3)
    const char* Ab = (const char*)XH + (size_t)n0 * 64;
    const char* Bb = (const char*)YH + (size_t)m0 * 64;
    const int dOf = t * 16;                     // 0..9216 within a part
    const int dSw = dOf ^ (((dOf >> 7) & 3) << 4);

    float4v acc[3][3];
    #pragma unroll
    for (int i = 0; i < 3; ++i)
        #pragma unroll
        for (int j = 0; j < 3; ++j)
            acc[i][j] = (float4v){0.f, 0.f, 0.f, 0.f};

    // ---- prologue: stage kt0 ----
    glds16(Ab + dSw,       smem + dOf);
    glds16(Ab + PLB + dSw, smem + 9216  + dOf);
    glds16(Bb + dSw,       smem + 18432 + dOf);
    glds16(Bb + PLB + dSw, smem + 27648 + dOf);
    __syncthreads();

    // swizzled fragment read offsets (row = 16k + lc; (row>>1)&3 == (lc>>1)&3)
    const int xr  = (lq * 16) ^ (((lc >> 1) & 3) << 4);
    const int axr = (wm * 48 + lc) * 64 + xr;
    const int bxr = (wn * 48 + lc) * 64 + xr;

    #pragma unroll 1
    for (int kt = 0; kt < 8; ++kt) {
        const char* cur = smem + (kt & 1) * 36864;

        if (kt < 7) {   // stage kt+1 into the other buffer (in flight across MFMAs)
            char* nxt = smem + ((kt + 1) & 1) * 36864;
            const size_t kb = (size_t)(kt + 1) * KTB;
            glds16(Ab + kb + dSw,       nxt + dOf);
            glds16(Ab + PLB + kb + dSw, nxt + 9216  + dOf);
            glds16(Bb + kb + dSw,       nxt + 18432 + dOf);
            glds16(Bb + PLB + kb + dSw, nxt + 27648 + dOf);
        }

        // ---- B register block: all 6 B frags live (24 VGPR), read ONCE ----
        half8v Bh[3], Br[3];
        #pragma unroll
        for (int cb = 0; cb < 3; ++cb) {
            Bh[cb] = *(const half8v*)(cur + 18432 + bxr + cb * 1024);
            Br[cb] = *(const half8v*)(cur + 27648 + bxr + cb * 1024);
        }

        // ---- rb-outer MFMA sweep: A read once per rb (6 reads) ----
        __builtin_amdgcn_s_setprio(1);
        #pragma unroll
        for (int rb = 0; rb < 3; ++rb) {
            half8v Ah = *(const half8v*)(cur +        axr + rb * 1024);
            half8v Ar = *(const half8v*)(cur + 9216 + axr + rb * 1024);
            #pragma unroll
            for (int cb = 0; cb < 3; ++cb) {
                float4v v = acc[rb][cb];
                v = __builtin_amdgcn_mfma_f32_16x16x32_f16(Ah, Bh[cb], v, 0, 0, 0);
                v = __builtin_amdgcn_mfma_f32_16x16x32_f16(Ah, Br[cb], v, 0, 0, 0);
                v = __builtin_amdgcn_mfma_f32_16x16x32_f16(Ar, Bh[cb], v, 0, 0, 0);
                acc[rb][cb] = v;
            }
        }
        __builtin_amdgcn_s_setprio(0);

        if (kt < 7) __syncthreads();   // drains next-tile DMA (had full MFMA phase)
    }

    // ---- epilogue: per-row argmax over this wave's 48 cols ----
    // C/D map: col=lane&15, row=lq*4+reg. Scale 2^16 is argmax-invariant.
    float bv[12]; int bc[12];
    #pragma unroll
    for (int s = 0; s < 12; ++s) { bv[s] = -INFINITY; bc[s] = 0; }

    #pragma unroll
    for (int rb = 0; rb < 3; ++rb)
        #pragma unroll
        for (int cb = 0; cb < 3; ++cb) {   // cb ascending = col ascending
            const int col = m0 + wn * 48 + cb * 16 + lc;
            #pragma unroll
            for (int r2 = 0; r2 < 4; ++r2) {
                float v = acc[rb][cb][r2];
                int s = rb * 4 + r2;
                if (v > bv[s]) { bv[s] = v; bc[s] = col; }
            }
        }

    // reduce across the 16 lc lanes (xor<16 stays in the quad-group)
    #pragma unroll
    for (int off = 1; off < 16; off <<= 1) {
        #pragma unroll
        for (int s = 0; s < 12; ++s) {
            float ov = __shfl_xor(bv[s], off, 64);
            int   oi = __shfl_xor(bc[s], off, 64);
            if (ov > bv[s] || (ov == bv[s] && oi < bc[s])) { bv[s] = ov; bc[s] = oi; }
        }
    }

    // combine 3 column waves per row via LDS table [144][3] (reuses buf0:
    // last read at kt6; every wave passed the kt6-end barrier).
    float* v2s = (float*)smem;             // 432 floats
    int*   i2s = (int*)(smem + 2048);      // 432 ints

    if (lc == 0) {
        #pragma unroll
        for (int rb = 0; rb < 3; ++rb)
            #pragma unroll
            for (int r2 = 0; r2 < 4; ++r2) {
                int row = wm * 48 + rb * 16 + lq * 4 + r2;
                v2s[row * 3 + wn] = bv[rb * 4 + r2];
                i2s[row * 3 + wn] = bc[rb * 4 + r2];
            }
    }
    __syncthreads();
    if (t < TS) {
        // wn ascending = col ascending: strict '>' keeps first-max semantics.
        float b = v2s[t * 3]; int bi = i2s[t * 3];
        #pragma unroll
        for (int q = 1; q < 3; ++q) {
            float v = v2s[t * 3 + q];
            if (v > b) { b = v; bi = i2s[t * 3 + q]; }
        }
        // packed atomic argmax: key = monotone(b)<<32 | ~col.
        // max key == max value; on equal value, max(~col) == min col ==
        // first-max semantics (identical to the old kred).
        unsigned uv = __float_as_uint(b);
        uv = (uv & 0x80000000u) ? ~uv : (uv | 0x80000000u);
        unsigned long long key =
            ((unsigned long long)uv << 32) | (unsigned)(0xFFFFFFFFu - (unsigned)bi);
        atomicMax(nnkey + n0 + t, key);
    }
}

// ---------------- Kernel 3: gather Y_sel + fused MSE loss ----------------
// y = (H + R) * 2^-8 (H/R same scale; error ~2^-22 relative).
__global__ __launch_bounds__(256) void kgather(
    const unsigned short* __restrict__ YH, const unsigned short* __restrict__ YR,
    const unsigned long long* __restrict__ nnkey,
    const float* __restrict__ Xf, float* __restrict__ Ysel,
    float* __restrict__ lacc)
{
    __shared__ float tile[64][65];
    __shared__ int   idxs[64];
    __shared__ float wsum[4];

    const int n0 = blockIdx.x * 64;
    const int d0 = blockIdx.y * 64;
    const int tid = threadIdx.x;

    if (tid < 64) {
        unsigned long long k = nnkey[n0 + tid];
        idxs[tid] = (int)(0xFFFFFFFFu - (unsigned)(k & 0xFFFFFFFFull));
    }
    __syncthreads();

    const int c  = tid & 63;
    const int r0 = tid >> 6;

    #pragma unroll
    for (int s = 0; s < 16; ++s) {
        int r = s * 4 + r0;
        int d = d0 + c;
        size_t off = (size_t)(d >> 5) * KCH + (size_t)idxs[r] * 32 + (d & 31);
        tile[r][c] = (h2f(YH[off]) + h2f(YR[off])) * (1.0f / 256.0f);
    }
    __syncthreads();

    float lsum = 0.0f;
    #pragma unroll
    for (int s = 0; s < 16; ++s) {
        int a = s * 4 + r0;
        int d = d0 + a;
        int n = n0 + c;
        float y = tile[c][a];          // stride-65: conflict-free
        float x = Xf[(size_t)d * NP + n];
        float diff = x - y;
        lsum = fmaf(diff, diff, lsum);
        Ysel[(size_t)d * NP + n] = y;  // coalesced over n
    }

    #pragma unroll
    for (int off = 32; off >= 1; off >>= 1)
        lsum += __shfl_xor(lsum, off, 64);
    if ((tid & 63) == 0) wsum[tid >> 6] = lsum;
    __syncthreads();
    if (tid == 0)
        atomicAdd(lacc, wsum[0] + wsum[1] + wsum[2] + wsum[3]);
}

// ---------------- Kernel 4: finalize loss ----------------
__global__ void kfin(const float* __restrict__ lacc, float* __restrict__ out)
{
    out[0] = lacc[0] * (1.0f / (float)DN);
}

extern "C" void kernel_launch(void* const* d_in, const int* in_sizes, int n_in,
                              void* d_out, int out_size, void* d_ws, size_t ws_size,
                              hipStream_t stream)
{
    const float* X = (const float*)d_in[0];   // X_features [1,256,96,96]
    const float* Y = (const float*)d_in[1];   // Y_features [1,256,96,96]
    // d_in[2], d_in[3] (images) are dead code in the reference — unused.

    float* out = (float*)d_out;
    float* Ysel_out = out + 1;          // output 1: Y_sel [1,D,N]
    float* Xf_out   = out + 1 + DN;     // output 2: Xf   [1,D,N]  (exact fp32)

    // Workspace (~19 MB). XH|XR and YH|YR MUST be contiguous pairs
    // (ksim derives R = H + 2*DN bytes). nnkey offset is 8*DN bytes (8B-aligned).
    unsigned short* XH = (unsigned short*)d_ws;   // DN halves each
    unsigned short* XR = XH + DN;
    unsigned short* YH = XR + DN;
    unsigned short* YR = YH + DN;
    unsigned long long* nnkey = (unsigned long long*)(YR + DN);   // NP u64
    float* lacc = (float*)(nnkey + NP);                           // 1

    static bool attr_done = false;
    if (!attr_done) {
        hipFuncSetAttribute(reinterpret_cast<const void*>(ksim),
                            hipFuncAttributeMaxDynamicSharedMemorySize, 73728);
        attr_done = true;
    }

    hipLaunchKernelGGL(kprep, dim3(NP / 64, 2), dim3(256), 0, stream,
                       X, Y, Xf_out, XH, XR, YH, YR, nnkey, lacc);
    hipLaunchKernelGGL(ksim, dim3(NTB, NTB), dim3(576), 73728, stream,
                       XH, YH, nnkey);
    hipLaunchKernelGGL(kgather, dim3(NP / 64, DC / 64), dim3(256), 0, stream,
                       YH, YR, nnkey, Xf_out, Ysel_out, lacc);
    hipLaunchKernelGGL(kfin, dim3(1), dim3(1), 0, stream, lacc, out);
}

// Round 15
// 252.768 us; speedup vs baseline: 1.2462x; 1.1335x over previous
//
#include <hip/hip_runtime.h>
#include <math.h>

// Problem constants (B=1 fixed by reference)
#define NP 9216          // S*S spatial positions
#define DC 256           // channels
#define DN (DC * NP)
#define NTB 36           // 9216 / 256 tiles per dim
#define KCH (NP * 32)    // halves per k-chunk section of a plane

#define FEPS 2.220446049250313e-16f

typedef __attribute__((ext_vector_type(8))) _Float16 half8v;
typedef __attribute__((ext_vector_type(4))) float   float4v;

union HU { _Float16 h; unsigned short u; };
__device__ __forceinline__ unsigned short f2h(float f) { HU x; x.h = (_Float16)f; return x.u; }
__device__ __forceinline__ float h2f(unsigned short s) { HU x; x.u = s; return (float)x.h; }

// Plane layout (k-major): half index off(n,k) = (k>>5)*KCH + n*32 + (k&31)
// Split (same scale): s' = v*inv*2^8; H = fp16(s'), R = fp16(s' - H).
// sim*2^16 = Hx.Hy + Hx.Ry + Rx.Hy (Rx.Ry dropped, ~2^-22 rel).
//
// R15 = R12 verbatim (best verified: 244.7us total, ksim 158.5us).
// Ledger of ksim levers (all counter-verified):
//   WINS: byte-dedup via 256^2 both-in-LDS (R7), B-reg-block rb-outer
//   (R8), swizzle bits (row>>1)&3 (R6), atomic-argmax kred-elimination
//   (R12). FAILS: 4/8-phase schedules (R1,R9: coarse phase-split without
//   fine interleave hurts), wave geometry 8/12w (R4,R10: 16w best),
//   32x32 shape (R13: 74x bank conflicts, 2-bit swizzle can't cover
//   32-row reads), smaller tiles (R14: 144^2 = -33%), 2-block overlap
//   (R14: register-impossible -- acc 64 + B 32 + addr ~= 128 unified
//   regs/wave caps CU at 16 waves = one block).
// Structure floor: 6-round makespan x 26.4us/tile, MfmaUtil ~37%.

// ---------------- Kernel 1: fused normalize + fp16 H/R split ----------------
__global__ __launch_bounds__(256) void kprep(
    const float* __restrict__ X, const float* __restrict__ Y,
    float* __restrict__ Xf_out,
    unsigned short* __restrict__ XH, unsigned short* __restrict__ XR,
    unsigned short* __restrict__ YH, unsigned short* __restrict__ YR,
    unsigned long long* __restrict__ nnkey, float* __restrict__ lacc)
{
    __shared__ float tile[64 * 257];   // (n, d) at n*257+d
    __shared__ float psum[4][64];
    __shared__ float invs[64];

    const int t = threadIdx.x;
    const bool isX = (blockIdx.y == 0);
    const float* src = isX ? X : Y;
    unsigned* hT = (unsigned*)(isX ? XH : YH);
    unsigned* rT = (unsigned*)(isX ? XR : YR);
    const int n0 = blockIdx.x * 64;

    if (blockIdx.x == 0 && blockIdx.y == 0 && t == 0) *lacc = 0.0f;
    if (isX && t < 64) nnkey[n0 + t] = 0ull;   // min key: any real value wins

    const int lane = t & 63;
    const int w    = t >> 6;      // wave id -> owns d-range [w*64, w*64+64)

    #pragma unroll 8
    for (int i = 0; i < 64; ++i) {
        int d = w * 64 + i;
        tile[lane * 257 + d] = src[(size_t)d * NP + n0 + lane];
    }
    float s = 0.0f;
    #pragma unroll 8
    for (int i = 0; i < 64; ++i) {
        float v = tile[lane * 257 + w * 64 + i];
        s = fmaf(v, v, s);
    }
    psum[w][lane] = s;
    __syncthreads();
    if (t < 64) {
        float tot = psum[0][t] + psum[1][t] + psum[2][t] + psum[3][t];
        invs[t] = 1.0f / (sqrtf(tot) + FEPS);
    }
    __syncthreads();

    // plane writes, k-major layout; coalesced uints.
    for (int kt = 0; kt < 8; ++kt) {
        #pragma unroll
        for (int p = 0; p < 4; ++p) {
            int idx = p * 256 + t;
            int n = idx >> 4;          // 0..63
            int u = idx & 15;          // uint within chunk (2 halves)
            float inv = invs[n] * 256.0f;
            int d = kt * 32 + 2 * u;
            float s0 = tile[n * 257 + d] * inv;
            float s1 = tile[n * 257 + d + 1] * inv;
            unsigned short h0 = f2h(s0), h1 = f2h(s1);
            unsigned short r0 = f2h(s0 - h2f(h0));
            unsigned short r1 = f2h(s1 - h2f(h1));
            size_t uo = (size_t)kt * (NP * 16) + (size_t)(n0 + n) * 16 + u;
            hT[uo] = (unsigned)h0 | ((unsigned)h1 << 16);
            rT[uo] = (unsigned)r0 | ((unsigned)r1 << 16);
        }
    }

    // exact fp32 Xf output ([d][n], coalesced over n)
    if (isX) {
        const float inv = invs[lane];
        #pragma unroll 8
        for (int i = 0; i < 64; ++i) {
            int d = w * 64 + i;
            Xf_out[(size_t)d * NP + n0 + lane] = tile[lane * 257 + d] * inv;
        }
    }
}

// ---------------- Kernel 2: 256x256 both-in-LDS MFMA GEMM + atomic argmax --
__device__ __forceinline__ void glds16(const char* g, char* l)
{
    __builtin_amdgcn_global_load_lds(
        (const __attribute__((address_space(1))) void*)g,
        (__attribute__((address_space(3))) void*)l, 16, 0, 0);
}

__global__ __launch_bounds__(1024, 4) void ksim(
    const unsigned short* __restrict__ XH,
    const unsigned short* __restrict__ YH,
    unsigned long long* __restrict__ nnkey)
{
    extern __shared__ char smem[];   // 2 x (A 32K | B 32K) = 128 KB

    const int t = threadIdx.x;
    const size_t PLB = 2 * (size_t)DN;            // H -> R plane byte offset
    const size_t KTB = 2 * (size_t)KCH;           // per-kt chunk byte stride

    // ---- XCD swizzle: 1296 blocks = 8 XCD x 162 (9 cols x 18 rows patch) --
    const int lid = blockIdx.y * NTB + blockIdx.x;
    const int xcd = lid & 7;
    const int r   = lid >> 3;                  // 0..161
    const int ti  = (xcd >> 2) * 18 + r / 9;   // row tile 0..35
    const int tj  = (xcd & 3) * 9 + r % 9;     // col tile 0..35
    const int n0  = ti * 256;                  // X rows
    const int m0  = tj * 256;                  // Y cols

    const int L = t & 63, wid = t >> 6;        // 16 waves: 4M x 4N
    const int wm = wid >> 2, wn = wid & 3;
    const int lc = L & 15,  lq = L >> 4;

    // staging: per-thread 16B seg; source inverse-swizzled (R6-verified
    // involution: XOR bits 4-5 of in-row offset with (row>>1)&3)
    const char* Ab = (const char*)XH + (size_t)n0 * 64;
    const char* Bb = (const char*)YH + (size_t)m0 * 64;
    const int dOf = t * 16;
    const int dSw = dOf ^ (((dOf >> 7) & 3) << 4);

    float4v acc[4][4];
    #pragma unroll
    for (int i = 0; i < 4; ++i)
        #pragma unroll
        for (int j = 0; j < 4; ++j)
            acc[i][j] = (float4v){0.f, 0.f, 0.f, 0.f};

    // ---- prologue: stage kt0 ----
    glds16(Ab + dSw,       smem + dOf);
    glds16(Ab + PLB + dSw, smem + 16384 + dOf);
    glds16(Bb + dSw,       smem + 32768 + dOf);
    glds16(Bb + PLB + dSw, smem + 49152 + dOf);
    __syncthreads();

    // swizzled fragment read offsets (row = strip + lc; (row>>1)&3 == (lc>>1)&3)
    const int xr  = (lq * 16) ^ (((lc >> 1) & 3) << 4);
    const int axr = (wm * 64 + lc) * 64 + xr;
    const int bxr = (wn * 64 + lc) * 64 + xr;

    #pragma unroll 1
    for (int kt = 0; kt < 8; ++kt) {
        const char* cur = smem + (kt & 1) * 65536;

        if (kt < 7) {   // stage kt+1 into the other buffer (in flight across MFMAs)
            char* nxt = smem + ((kt + 1) & 1) * 65536;
            const size_t kb = (size_t)(kt + 1) * KTB;
            glds16(Ab + kb + dSw,       nxt + dOf);
            glds16(Ab + PLB + kb + dSw, nxt + 16384 + dOf);
            glds16(Bb + kb + dSw,       nxt + 32768 + dOf);
            glds16(Bb + PLB + kb + dSw, nxt + 49152 + dOf);
        }

        // ---- B register block: all 8 B frags live (32 VGPR), read ONCE ----
        half8v Bh[4], Br[4];
        #pragma unroll
        for (int cb = 0; cb < 4; ++cb) {
            Bh[cb] = *(const half8v*)(cur + 32768 + bxr + cb * 1024);
            Br[cb] = *(const half8v*)(cur + 49152 + bxr + cb * 1024);
        }

        // ---- rb-outer MFMA sweep: A read once per rb (8 reads) ----
        __builtin_amdgcn_s_setprio(1);
        #pragma unroll
        for (int rb = 0; rb < 4; ++rb) {
            half8v Ah = *(const half8v*)(cur +         axr + rb * 1024);
            half8v Ar = *(const half8v*)(cur + 16384 + axr + rb * 1024);
            #pragma unroll
            for (int cb = 0; cb < 4; ++cb) {
                float4v v = acc[rb][cb];
                v = __builtin_amdgcn_mfma_f32_16x16x32_f16(Ah, Bh[cb], v, 0, 0, 0);
                v = __builtin_amdgcn_mfma_f32_16x16x32_f16(Ah, Br[cb], v, 0, 0, 0);
                v = __builtin_amdgcn_mfma_f32_16x16x32_f16(Ar, Bh[cb], v, 0, 0, 0);
                acc[rb][cb] = v;
            }
        }
        __builtin_amdgcn_s_setprio(0);

        if (kt < 7) __syncthreads();   // drains next-tile DMA (had full MFMA phase)
    }

    // ---- epilogue: per-row argmax over this wave's 64 cols ----
    // C/D map: col=lane&15, row=lq*4+reg. Scale 2^16 is argmax-invariant.
    float bv[16]; int bc[16];
    #pragma unroll
    for (int s = 0; s < 16; ++s) { bv[s] = -INFINITY; bc[s] = 0; }

    #pragma unroll
    for (int rb = 0; rb < 4; ++rb)
        #pragma unroll
        for (int cb = 0; cb < 4; ++cb) {   // cb ascending = col ascending
            const int col = m0 + wn * 64 + cb * 16 + lc;
            #pragma unroll
            for (int r2 = 0; r2 < 4; ++r2) {
                float v = acc[rb][cb][r2];
                int s = rb * 4 + r2;
                if (v > bv[s]) { bv[s] = v; bc[s] = col; }
            }
        }

    // reduce across the 16 lc lanes (xor<16 stays in the quad-group)
    #pragma unroll
    for (int off = 1; off < 16; off <<= 1) {
        #pragma unroll
        for (int s = 0; s < 16; ++s) {
            float ov = __shfl_xor(bv[s], off, 64);
            int   oi = __shfl_xor(bc[s], off, 64);
            if (ov > bv[s] || (ov == bv[s] && oi < bc[s])) { bv[s] = ov; bc[s] = oi; }
        }
    }

    // combine 4 column waves per row via LDS table [256][4] (reuses buf0:
    // last read at kt6; every wave passed the kt6-end barrier).
    float* v2s = (float*)smem;
    int*   i2s = (int*)(smem + 4096);

    if (lc == 0) {
        #pragma unroll
        for (int rb = 0; rb < 4; ++rb)
            #pragma unroll
            for (int r2 = 0; r2 < 4; ++r2) {
                int row = wm * 64 + rb * 16 + lq * 4 + r2;
                v2s[row * 4 + wn] = bv[rb * 4 + r2];
                i2s[row * 4 + wn] = bc[rb * 4 + r2];
            }
    }
    __syncthreads();
    if (t < 256) {
        // wn ascending = col ascending: strict '>' keeps first-max semantics.
        float b = v2s[t * 4]; int bi = i2s[t * 4];
        #pragma unroll
        for (int q = 1; q < 4; ++q) {
            float v = v2s[t * 4 + q];
            if (v > b) { b = v; bi = i2s[t * 4 + q]; }
        }
        // packed atomic argmax: key = monotone(b)<<32 | ~col.
        // max key == max value; on equal value, max(~col) == min col ==
        // first-max semantics (identical to the old kred).
        unsigned uv = __float_as_uint(b);
        uv = (uv & 0x80000000u) ? ~uv : (uv | 0x80000000u);
        unsigned long long key =
            ((unsigned long long)uv << 32) | (unsigned)(0xFFFFFFFFu - (unsigned)bi);
        atomicMax(nnkey + n0 + t, key);
    }
}

// ---------------- Kernel 3: gather Y_sel + fused MSE loss ----------------
// y = (H + R) * 2^-8 (H/R same scale; error ~2^-22 relative).
__global__ __launch_bounds__(256) void kgather(
    const unsigned short* __restrict__ YH, const unsigned short* __restrict__ YR,
    const unsigned long long* __restrict__ nnkey,
    const float* __restrict__ Xf, float* __restrict__ Ysel,
    float* __restrict__ lacc)
{
    __shared__ float tile[64][65];
    __shared__ int   idxs[64];
    __shared__ float wsum[4];

    const int n0 = blockIdx.x * 64;
    const int d0 = blockIdx.y * 64;
    const int tid = threadIdx.x;

    if (tid < 64) {
        unsigned long long k = nnkey[n0 + tid];
        idxs[tid] = (int)(0xFFFFFFFFu - (unsigned)(k & 0xFFFFFFFFull));
    }
    __syncthreads();

    const int c  = tid & 63;
    const int r0 = tid >> 6;

    #pragma unroll
    for (int s = 0; s < 16; ++s) {
        int r = s * 4 + r0;
        int d = d0 + c;
        size_t off = (size_t)(d >> 5) * KCH + (size_t)idxs[r] * 32 + (d & 31);
        tile[r][c] = (h2f(YH[off]) + h2f(YR[off])) * (1.0f / 256.0f);
    }
    __syncthreads();

    float lsum = 0.0f;
    #pragma unroll
    for (int s = 0; s < 16; ++s) {
        int a = s * 4 + r0;
        int d = d0 + a;
        int n = n0 + c;
        float y = tile[c][a];          // stride-65: conflict-free
        float x = Xf[(size_t)d * NP + n];
        float diff = x - y;
        lsum = fmaf(diff, diff, lsum);
        Ysel[(size_t)d * NP + n] = y;  // coalesced over n
    }

    #pragma unroll
    for (int off = 32; off >= 1; off >>= 1)
        lsum += __shfl_xor(lsum, off, 64);
    if ((tid & 63) == 0) wsum[tid >> 6] = lsum;
    __syncthreads();
    if (tid == 0)
        atomicAdd(lacc, wsum[0] + wsum[1] + wsum[2] + wsum[3]);
}

// ---------------- Kernel 4: finalize loss ----------------
__global__ void kfin(const float* __restrict__ lacc, float* __restrict__ out)
{
    out[0] = lacc[0] * (1.0f / (float)DN);
}

extern "C" void kernel_launch(void* const* d_in, const int* in_sizes, int n_in,
                              void* d_out, int out_size, void* d_ws, size_t ws_size,
                              hipStream_t stream)
{
    const float* X = (const float*)d_in[0];   // X_features [1,256,96,96]
    const float* Y = (const float*)d_in[1];   // Y_features [1,256,96,96]
    // d_in[2], d_in[3] (images) are dead code in the reference — unused.

    float* out = (float*)d_out;
    float* Ysel_out = out + 1;          // output 1: Y_sel [1,D,N]
    float* Xf_out   = out + 1 + DN;     // output 2: Xf   [1,D,N]  (exact fp32)

    // Workspace (~19 MB). XH|XR and YH|YR MUST be contiguous pairs
    // (ksim derives R = H + 2*DN bytes). nnkey offset is 8*DN bytes (8B-aligned).
    unsigned short* XH = (unsigned short*)d_ws;   // DN halves each
    unsigned short* XR = XH + DN;
    unsigned short* YH = XR + DN;
    unsigned short* YR = YH + DN;
    unsigned long long* nnkey = (unsigned long long*)(YR + DN);   // NP u64
    float* lacc = (float*)(nnkey + NP);                           // 1

    static bool attr_done = false;
    if (!attr_done) {
        hipFuncSetAttribute(reinterpret_cast<const void*>(ksim),
                            hipFuncAttributeMaxDynamicSharedMemorySize, 131072);
        attr_done = true;
    }

    hipLaunchKernelGGL(kprep, dim3(NP / 64, 2), dim3(256), 0, stream,
                       X, Y, Xf_out, XH, XR, YH, YR, nnkey, lacc);
    hipLaunchKernelGGL(ksim, dim3(NTB, NTB), dim3(1024), 131072, stream,
                       XH, YH, nnkey);
    hipLaunchKernelGGL(kgather, dim3(NP / 64, DC / 64), dim3(256), 0, stream,
                       YH, YR, nnkey, Xf_out, Ysel_out, lacc);
    hipLaunchKernelGGL(kfin, dim3(1), dim3(1), 0, stream, lacc, out);
}